// Round 4
// baseline (890.802 us; speedup 1.0000x reference)
//
#include <hip/hip_runtime.h>

typedef unsigned char u8;
typedef unsigned int u32;
using f32x4 = __attribute__((ext_vector_type(4))) float;

#define E4M3_AMAX 216.0f
#define FP8_MAXV 240.0f

#define BM 128
#define BN 128
#define BK 64   // fp8 bytes along K per tile

#define GLD_LDS16(g, l) \
    __builtin_amdgcn_global_load_lds((const __attribute__((address_space(1))) void*)(g), \
                                     (__attribute__((address_space(3))) void*)(l), 16, 0, 0)

// ---------------- fused abs-max reduction ------------------------------------
// float fmax form: fabs folds into the max as an input modifier (~4 VALU per
// float4 vs ~12 for the u32 cmp/select chain). Bit-exact for non-NaN input;
// final atomicMax compares the monotone nonneg-float bit pattern.
// blocks [0, blocksA) reduce tensor a -> outa; the rest reduce b -> outb.
__global__ void maxabs2_kernel(const float* __restrict__ a, long na4, u32* __restrict__ outa,
                               const float* __restrict__ b, long nb4, u32* __restrict__ outb,
                               int blocksA) {
    const float4* x4;
    long n4;
    u32* out;
    long bid, nb;
    if ((int)blockIdx.x < blocksA) {
        x4 = (const float4*)a; n4 = na4; out = outa; bid = blockIdx.x; nb = blocksA;
    } else {
        x4 = (const float4*)b; n4 = nb4; out = outb; bid = blockIdx.x - blocksA; nb = gridDim.x - blocksA;
    }
    long stride = nb * blockDim.x;
    long i = bid * blockDim.x + threadIdx.x;
    float m = 0.0f;
    for (long j = i; j < n4; j += stride) {
        float4 v = x4[j];
        float m01 = fmaxf(fabsf(v.x), fabsf(v.y));
        float m23 = fmaxf(fabsf(v.z), fabsf(v.w));
        m = fmaxf(m, fmaxf(m01, m23));
    }
    #pragma unroll
    for (int off = 32; off > 0; off >>= 1)
        m = fmaxf(m, __shfl_down(m, off, 64));
    __shared__ float sm[8];
    int wave = threadIdx.x >> 6, lane = threadIdx.x & 63;
    if (lane == 0) sm[wave] = m;
    __syncthreads();
    if (threadIdx.x == 0) {
        float r = sm[0];
        int nw = blockDim.x >> 6;
        for (int w = 1; w < nw; ++w) r = fmaxf(r, sm[w]);
        atomicMax(out, __float_as_uint(r));
    }
}

// ---------------- fused quantize f32 -> e4m3fn bytes (HW RNE cvt) ------------
// Coalesced: each thread one float4 load (16B) -> one int store (4B).
// blocks [0, blocksA) do tensor a, the rest tensor b.
__global__ void quant2_kernel(const float* __restrict__ a, u8* __restrict__ ya, long na4,
                              const float* __restrict__ b, u8* __restrict__ yb, long nb4,
                              const u32* __restrict__ maxbits, int blocksA) {
    const float4* x4;
    int* y4;
    long n4, bid, nb;
    float mx;
    if ((int)blockIdx.x < blocksA) {
        x4 = (const float4*)a; y4 = (int*)ya; n4 = na4; bid = blockIdx.x; nb = blocksA;
        mx = __uint_as_float(maxbits[0]);
    } else {
        x4 = (const float4*)b; y4 = (int*)yb; n4 = nb4; bid = blockIdx.x - blocksA; nb = gridDim.x - blocksA;
        mx = __uint_as_float(maxbits[1]);
    }
    float scale = E4M3_AMAX / mx;
    long stride = nb * blockDim.x;
    long i = bid * blockDim.x + threadIdx.x;
    for (long j = i; j < n4; j += stride) {
        float4 v = x4[j];
        float pa = fminf(fmaxf(v.x * scale, -FP8_MAXV), FP8_MAXV);
        float pb = fminf(fmaxf(v.y * scale, -FP8_MAXV), FP8_MAXV);
        float pc = fminf(fmaxf(v.z * scale, -FP8_MAXV), FP8_MAXV);
        float pd = fminf(fmaxf(v.w * scale, -FP8_MAXV), FP8_MAXV);
        int p = 0;
        p = __builtin_amdgcn_cvt_pk_fp8_f32(pa, pb, p, false);  // bytes 0,1
        p = __builtin_amdgcn_cvt_pk_fp8_f32(pc, pd, p, true);   // bytes 2,3
        y4[j] = p;
    }
}

// ---------------- fp8 GEMM: C[m,n] = sum_k A8[m,k]*W8[n,k], dequant + bias ---
// 128x128 block tile, 256 threads (4 waves), 64x64 per wave (4x4 of 16x16x32).
//
// Kept from earlier rounds:
//  - LDS 16B-block XOR swizzle: colblock16 ^= (row>>1)&3 applied to BOTH the
//    staging SOURCE (global col) and the fragment READ address; LDS dest stays
//    linear (global_load_lds requirement). ds_read_b64 hits every bank 4x.
//  - Natural blockIdx mapping (XCD = blockIdx.x % 8 keeps each XCD's 2MB
//    B-panel L2-resident; chunked swizzle regressed FETCH 3x in round 2).
//
// This revision (T3/T4 minimum): 3-buffer depth-2 pipeline with counted
// s_waitcnt vmcnt(4) + raw s_barrier, ONE barrier per tile. Loads stay in
// flight across the barrier instead of the vmcnt(0) drain __syncthreads emits.
// Race ledger: each wave waits its OWN 4 oldest loads (its tile-t share)
// BEFORE the barrier -> after the barrier all waves' tile-t data is in LDS.
// stage(t+2) overwrites the buffer computed at t-1; all its reads completed
// before this barrier (a wave issues all MFMAs, hence all lgkm-waited
// ds_reads, before reaching the next barrier). Tail: t=NT-1 waits vmcnt(0).
__device__ __forceinline__ void stage_tile(const u8* gA, const u8* gB, u8* lA, u8* lB, int K) {
    GLD_LDS16(gA,                  lA);
    GLD_LDS16(gA + (size_t)64 * K, lA + 4096);   // rows +64
    GLD_LDS16(gB,                  lB);
    GLD_LDS16(gB + (size_t)64 * K, lB + 4096);
}

__device__ __forceinline__ void compute_tile(const u8* Asb, const u8* Bsb, f32x4 acc[4][4],
                                             int wm, int wn, int fr, int quad, int swzr) {
    #pragma unroll
    for (int ks = 0; ks < 2; ++ks) {
        const int colx = (ks * 32 + quad * 8) ^ (swzr << 4);  // swizzled col bytes
        long a[4], b[4];
        #pragma unroll
        for (int i = 0; i < 4; ++i) {
            a[i] = *(const long*)(Asb + (wm + i * 16 + fr) * BK + colx);
            b[i] = *(const long*)(Bsb + (wn + i * 16 + fr) * BK + colx);
        }
        #pragma unroll
        for (int i = 0; i < 4; ++i)
            #pragma unroll
            for (int j = 0; j < 4; ++j)
                acc[i][j] = __builtin_amdgcn_mfma_f32_16x16x32_fp8_fp8(a[i], b[j], acc[i][j], 0, 0, 0);
    }
}

__global__ __launch_bounds__(256) void gemm_fp8_kernel(
    const u8* __restrict__ A,   // [M,K] fp8
    const u8* __restrict__ B,   // [N,K] fp8 (weight, K-contiguous = B^T form)
    const float* __restrict__ bias,
    const u32* __restrict__ scales,
    float* __restrict__ C, int M, int N, int K)
{
    // 3-deep pipeline: per buffer As (8KB) + Bs (8KB); total 48KB
    __shared__ u8 smem[3][2 * BM * BK];

    const int tid = threadIdx.x;
    const int wave = tid >> 6;
    const int lane = tid & 63;
    const int fr = lane & 15;      // frag row (A) / col (B/D)
    const int quad = lane >> 4;    // 0..3

    const int bm = blockIdx.y * BM;
    const int bn = blockIdx.x * BN;

    const int wm = (wave >> 1) * 64;
    const int wn = (wave & 1) * 64;

    f32x4 acc[4][4] = {};

    // staging: each wave fills 2 chunks of 1024B per matrix per tile
    // lane i writes LDS [chunk*1024 + i*16] (LINEAR dest);
    // source row = 16*wave + i/4; source 16B-col = (i&3) ^ ((row>>1)&3)
    const int srow = 16 * wave + (lane >> 2);
    const int swzs = (lane >> 3) & 3;                 // == (srow>>1)&3 ; also for srow+64
    const int scol = ((lane & 3) ^ swzs) * 16;
    const u8* gA = A + (size_t)(bm + srow) * K + scol;
    const u8* gB = B + (size_t)(bn + srow) * K + scol;
    const int lofs = wave * 1024;                     // wave-uniform LDS base offset

    // read-side swizzle: row = wm + i*16 + fr, (row>>1)&3 == (fr>>1)&3 for all i,wm
    const int swzr = (fr >> 1) & 3;

    const int NT = K / BK;                            // 64 for K=4096

    // prologue: stage tiles 0,1 into buffers 0,1 (8 loads in flight)
    stage_tile(gA,      gB,      smem[0] + lofs, smem[0] + BM * BK + lofs, K);
    stage_tile(gA + BK, gB + BK, smem[1] + lofs, smem[1] + BM * BK + lofs, K);

    const u8* cB_ = smem[0];   // current
    const u8* nB_ = smem[1];   // next (staged)
    const u8* pB_ = smem[2];   // prefetch target this iteration

    for (int t = 0; t < NT; ++t) {
        // wait own tile-t loads (oldest 4 of <=8 outstanding), then barrier
        if (t < NT - 1) { asm volatile("s_waitcnt vmcnt(4)" ::: "memory"); }
        else            { asm volatile("s_waitcnt vmcnt(0)" ::: "memory"); }
        __builtin_amdgcn_s_barrier();
        __builtin_amdgcn_sched_barrier(0);

        // issue next-next tile's loads into the buffer freed at t-1
        if (t + 2 < NT)
            stage_tile(gA + (size_t)(t + 2) * BK, gB + (size_t)(t + 2) * BK,
                       (u8*)pB_ + lofs, (u8*)pB_ + BM * BK + lofs, K);

        __builtin_amdgcn_s_setprio(1);
        compute_tile(cB_, cB_ + BM * BK, acc, wm, wn, fr, quad, swzr);
        __builtin_amdgcn_s_setprio(0);

        const u8* tmp = cB_; cB_ = nB_; nB_ = pB_; pB_ = tmp;  // rotate
    }

    // dequant epilogue: out = acc * (1/i_scale) * (1/w_scale) + bias
    const float mi = __uint_as_float(scales[0]);
    const float mw = __uint_as_float(scales[1]);
    const float i_scale = E4M3_AMAX / mi;
    const float w_scale = E4M3_AMAX / mw;
    const float deq = (1.0f / i_scale) * (1.0f / w_scale);

    #pragma unroll
    for (int i = 0; i < 4; ++i) {
        const int row0 = bm + wm + i * 16 + quad * 4;
        #pragma unroll
        for (int j = 0; j < 4; ++j) {
            const int col = bn + wn + j * 16 + fr;
            const float bv = bias[col];
            #pragma unroll
            for (int rg = 0; rg < 4; ++rg) {
                C[(size_t)(row0 + rg) * N + col] = acc[i][j][rg] * deq + bv;
            }
        }
    }
}

extern "C" void kernel_launch(void* const* d_in, const int* in_sizes, int n_in,
                              void* d_out, int out_size, void* d_ws, size_t ws_size,
                              hipStream_t stream) {
    const float* inp    = (const float*)d_in[0];
    const float* weight = (const float*)d_in[1];
    const float* bias   = (const float*)d_in[2];
    float* out = (float*)d_out;

    const int N = in_sizes[2];                        // 4096
    const int K = in_sizes[1] / N;                    // 4096
    const long icount = in_sizes[0];                  // 67108864
    const int M = (int)(icount / K);                  // 16384
    const long wcount = (long)N * K;

    u32* scales = (u32*)d_ws;
    u8* x8 = (u8*)d_ws + 256;
    u8* w8 = x8 + (size_t)M * K;

    // zero the amax accumulators (ws is poisoned 0xAA before each call)
    hipMemsetAsync(d_ws, 0, 16, stream);

    // fused abs-max: blocks [0,2048) -> inp, [2048,2560) -> weight
    maxabs2_kernel<<<2560, 256, 0, stream>>>(inp, icount / 4, scales + 0,
                                             weight, wcount / 4, scales + 1, 2048);
    // fused quantize: coalesced float4 load -> int store
    quant2_kernel<<<2560, 256, 0, stream>>>(inp, x8, icount / 4,
                                            weight, w8, wcount / 4, scales, 2048);

    dim3 grid(N / BN, M / BM);
    gemm_fp8_kernel<<<grid, 256, 0, stream>>>(x8, w8, bias, scales, out, M, N, K);
}